// Round 8
// baseline (313.266 us; speedup 1.0000x reference)
//
#include <hip/hip_runtime.h>
#include <hip/hip_bf16.h>

#define C2 340
#define HID 170
#define NB 4
#define HGT 256
#define WID 256
#define HW (HGT*WID)
#define BAND 128
#define ST 1040   // LDS row stride (u16) for 1024-px tiles, conflict-buster

typedef unsigned short u16;
typedef unsigned int u32;
typedef float f32x4 __attribute__((ext_vector_type(4)));
typedef short s16x8 __attribute__((ext_vector_type(8)));

__device__ __forceinline__ float bf2f(u16 u) {
  union { u32 i; float f; } v; v.i = ((u32)u) << 16; return v.f;
}
__device__ __forceinline__ u16 f2bf(float f) {
  union { float f; u32 i; } v; v.f = f;
  u32 x = v.i;
  return (u16)((x + 0x7fffu + ((x >> 16) & 1u)) >> 16);
}

__device__ const float COSTAB[8] = {1.f, 0.70710678118654752f, 0.f, -0.70710678118654752f,
                                    -1.f, -0.70710678118654752f, 0.f, 0.70710678118654752f};

// ------- prepass: transpose x [b][64][HW] f32 -> xt [b][pix][64] bf16 -------
__global__ __launch_bounds__(256) void k_xt(const float* __restrict__ x,
                                            u16* __restrict__ xt) {
  const int b = blockIdx.x >> 8;
  const int pix = ((blockIdx.x & 255) << 8) + threadIdx.x;
  const float* xp = x + (size_t)b * 64 * HW + pix;
  float v[64];
  #pragma unroll
  for (int c = 0; c < 64; ++c) v[c] = xp[(size_t)c * HW];
  u32 pk[32];
  #pragma unroll
  for (int i = 0; i < 32; ++i)
    pk[i] = (u32)f2bf(v[2*i]) | ((u32)f2bf(v[2*i+1]) << 16);
  uint4* op = (uint4*)(xt + ((size_t)b * 65536 + pix) * 64);
  #pragma unroll
  for (int i = 0; i < 8; ++i)
    op[i] = make_uint4(pk[4*i], pk[4*i+1], pk[4*i+2], pk[4*i+3]);
}

// ------- prepass: W_in [340][64] f32 -> bf16 A-fragments, padded to 352 rows -------
__global__ __launch_bounds__(256) void k_wfrag(const float* __restrict__ w_in,
                                               u16* __restrict__ wf) {
  for (int e = threadIdx.x; e < 22*2*64*8; e += 256) {
    const int r = e & 7;
    const int l = (e >> 3) & 63;
    const int ts = e >> 9;
    const int s = ts & 1, t = ts >> 1;
    const int m = t*16 + (l & 15);
    const int k = s*32 + ((l >> 4) << 3) + r;
    wf[e] = (m < C2) ? f2bf(w_in[m*64 + k]) : (u16)0;
  }
}

// ------- prepass: w_out [64][170] f32 -> bf16 A-fragments, K padded to 192 -------
__global__ __launch_bounds__(256) void k_wofrag(const float* __restrict__ w_out,
                                                u16* __restrict__ wof) {
  for (int e = threadIdx.x; e < 4*6*64*8; e += 256) {
    const int r = e & 7;
    const int l = (e >> 3) & 63;
    const int mk = e >> 9;
    const int kc = mk % 6, mt = mk / 6;
    const int m = mt*16 + (l & 15);
    const int k = kc*32 + ((l >> 4) << 3) + r;
    wof[e] = (k < HID) ? f2bf(w_out[m*HID + k]) : (u16)0;
  }
}

// ------- prepass: build per-channel conv matrix in MFMA B-fragment order -------
__global__ __launch_bounds__(256) void k_mfrag(const float* __restrict__ fw,
                                               u16* __restrict__ mf) {
  __shared__ float kern[64];
  const int c = blockIdx.x;
  if (threadIdx.x < 64) {
    const int a = threadIdx.x >> 3, bb = threadIdx.x & 7;
    float acc = 0.f;
    for (int u = 0; u < 8; ++u)
      for (int v = 0; v < 8; ++v) {
        const float wv = (v <= 4) ? fw[c*40 + u*5 + v]
                                  : fw[c*40 + ((8-u)&7)*5 + (8-v)];
        acc += wv * COSTAB[(u*a + v*bb) & 7];
      }
    kern[threadIdx.x] = acc * (1.f/64.f);
  }
  __syncthreads();
  #pragma unroll
  for (int q = 0; q < 16; ++q) {
    const int e = q * 256 + threadIdx.x;
    const int r = e & 7;
    const int l = (e >> 3) & 63;
    const int sb = e >> 9;
    const int s = sb & 1, nblk = sb >> 1;
    const int k = s*32 + ((l >> 4) << 3) + r;
    const int a = k >> 3, bcol = k & 7;
    const int n = nblk*16 + (l & 15);
    const int i = n >> 3, j = n & 7;
    mf[(size_t)c * 4096 + e] = f2bf(kern[(((i - a) & 7) << 3) + ((j - bcol) & 7)]);
  }
}

// ======= FUSED: project_in (MFMA) + per-channel 8x8 circular conv (MFMA) =======
// block = 8 rows x 128 cols x all 340 channels; 512 threads (8 waves)
__global__ __launch_bounds__(512) void k_fused(const u16* __restrict__ xt,
                                               const u16* __restrict__ wfrag,
                                               const u16* __restrict__ mfrag,
                                               u16* __restrict__ mid) {
  __shared__ __align__(16) u16 stA[16 * ST];      // projin tile [16ch][1024px(+pad)]
  __shared__ __align__(16) u16 stB[16 * ST];      // pconv  tile
  const int bid = blockIdx.x;
  const int b   = bid >> 6;
  const int s   = (bid >> 1) & 31;
  const int hf  = bid & 1;
  const int row0 = s * 8, col0 = hf * 128;

  const int w = threadIdx.x >> 6;                 // wave 0..7 == region row
  const int lane = threadIdx.x & 63;
  const int lm = lane & 15, lh = lane >> 4;

  // xt B-fragments for this wave's row: 8 col-groups x 2 k-steps (held in regs)
  s16x8 Bf[8][2];
  {
    const size_t pbase = ((size_t)b * 65536 + (size_t)(row0 + w) * 256 + col0) * 64;
    #pragma unroll
    for (int j = 0; j < 8; ++j) {
      const u16* p = xt + pbase + (j*16 + lm)*64 + lh*8;
      Bf[j][0] = *(const s16x8*)(p);
      Bf[j][1] = *(const s16x8*)(p + 32);
    }
  }

  for (int t = 0; t < 22; ++t) {
    // --- prefetch this tile's weights (consumed after barriers) ---
    const s16x8 A0 = *(const s16x8*)(wfrag + ((t*2 + 0)*64 + lane)*8);
    const s16x8 A1 = *(const s16x8*)(wfrag + ((t*2 + 1)*64 + lane)*8);
    s16x8 Bc[2][4][2];
    #pragma unroll
    for (int q = 0; q < 2; ++q) {
      const int ch = t*16 + w*2 + q;
      if (ch < C2) {
        const u16* mfc = mfrag + (size_t)ch * 4096;
        #pragma unroll
        for (int nb = 0; nb < 4; ++nb)
          #pragma unroll
          for (int ks = 0; ks < 2; ++ks)
            Bc[q][nb][ks] = *(const s16x8*)(mfc + ((nb*2 + ks)*64 + lane)*8);
      }
    }
    __syncthreads();                              // B1: stA/stB free from prev tile
    // --- P1+P2: projin MFMA, scatter [16ch x 1024px] to stA ---
    #pragma unroll
    for (int j = 0; j < 8; ++j) {
      f32x4 acc = {0.f,0.f,0.f,0.f};
      acc = __builtin_amdgcn_mfma_f32_16x16x32_bf16(A0, Bf[j][0], acc, 0,0,0);
      acc = __builtin_amdgcn_mfma_f32_16x16x32_bf16(A1, Bf[j][1], acc, 0,0,0);
      u16* sp = stA + w*128 + j*16 + lm;          // row w, col j*16+lm
      #pragma unroll
      for (int r = 0; r < 4; ++r)
        sp[(lh*4 + r) * ST] = f2bf(acc[r]);       // st row = local channel
    }
    __syncthreads();                              // B2
    // --- P3: pconv for this wave's 2 channels ---
    #pragma unroll
    for (int q = 0; q < 2; ++q) {
      const int cl = w*2 + q;
      const int ch = t*16 + cl;
      if (ch < C2) {
        const u16* ap = stA + cl*ST + lh*128 + lm*8;       // k-rows lh / 4+lh
        const s16x8 Ap0 = *(const s16x8*)(ap);
        const s16x8 Ap1 = *(const s16x8*)(ap + 4*128);
        u16* bp = stB + cl*ST + (lm >> 3)*128 + lh*32 + (lm & 7);
        #pragma unroll
        for (int nb = 0; nb < 4; ++nb) {
          f32x4 acc = {0.f,0.f,0.f,0.f};
          acc = __builtin_amdgcn_mfma_f32_16x16x32_bf16(Ap0, Bc[q][nb][0], acc, 0,0,0);
          acc = __builtin_amdgcn_mfma_f32_16x16x32_bf16(Ap1, Bc[q][nb][1], acc, 0,0,0);
          #pragma unroll
          for (int r = 0; r < 4; ++r)
            bp[nb*256 + r*8] = f2bf(acc[r]);
        }
      }
    }
    __syncthreads();                              // B3
    // --- P4: coalesced write stB -> mid ---
    #pragma unroll
    for (int k = 0; k < 4; ++k) {
      const int u = threadIdx.x * 4 + k;          // 2048 uint4 total
      const int cl = u >> 7, rem = u & 127;
      const int i = rem >> 4, sg = rem & 15;
      const int ch = t*16 + cl;
      if (ch < C2) {
        const uint4 v = *(const uint4*)(stB + cl*ST + i*128 + sg*8);
        u16* dst = mid + ((size_t)(b*C2 + ch)) * HW + (size_t)(row0 + i) * WID + col0 + sg*8;
        *(uint4*)dst = v;
      }
    }
  }
}

// ------- K3a: depthwise 3x3 + exact GELU gate, band-wise, coalesced -------
__global__ __launch_bounds__(256) void k_gate(const u16* __restrict__ mid,
                                              const float* __restrict__ w_dw,
                                              u16* __restrict__ gbuf, int hb) {
  __shared__ __align__(16) u16 sh[2][18][272];
  const int s  = blockIdx.x & 7;
  const int bc = blockIdx.x >> 3;
  const int c  = bc % HID, b = bc / HID;
  const int h0 = hb + s * 16;

  u32* shw = (u32*)sh;
  for (int i = threadIdx.x; i < 2*18*136; i += 256) shw[i] = 0;
  __syncthreads();
  for (int i = threadIdx.x; i < 2*18*32; i += 256) {
    const int k = i & 31;
    const int r = (i >> 5) % 18;
    const int ch2 = i / (18*32);
    const int h = h0 + r - 1;
    if (h >= 0 && h < HGT) {
      const u16* src = mid + ((size_t)(b*C2 + c + ch2*HID)) * HW + (size_t)h * WID + k*8;
      *(uint4*)&sh[ch2][r][8 + k*8] = *(const uint4*)src;
    }
  }
  __syncthreads();

  const int cc = threadIdx.x;
  const float* wd1 = w_dw + c * 9;
  const float* wd2 = w_dw + (c + HID) * 9;
  u16* gp = gbuf + (((size_t)(b*HID + c)) * BAND + (h0 - hb)) * WID + cc;

  float A[3][3], B2[3][3];
  #pragma unroll
  for (int ri = 0; ri < 2; ++ri)
    #pragma unroll
    for (int j = 0; j < 3; ++j) {
      A[ri][j]  = bf2f(sh[0][ri][7 + cc + j]);
      B2[ri][j] = bf2f(sh[1][ri][7 + cc + j]);
    }
  #pragma unroll 4
  for (int r = 0; r < 16; ++r) {
    #pragma unroll
    for (int j = 0; j < 3; ++j) {
      A[2][j]  = bf2f(sh[0][r+2][7 + cc + j]);
      B2[2][j] = bf2f(sh[1][r+2][7 + cc + j]);
    }
    float a1 = 0.f, a2 = 0.f;
    #pragma unroll
    for (int ri = 0; ri < 3; ++ri)
      #pragma unroll
      for (int j = 0; j < 3; ++j) {
        a1 += wd1[ri*3 + j] * A[ri][j];
        a2 += wd2[ri*3 + j] * B2[ri][j];
      }
    const float g = 0.5f * a1 * (1.f + erff(a1 * 0.70710678118654752f)) * a2;
    gp[(size_t)r * WID] = f2bf(g);
    #pragma unroll
    for (int j = 0; j < 3; ++j) {
      A[0][j] = A[1][j];  A[1][j] = A[2][j];
      B2[0][j] = B2[1][j]; B2[1][j] = B2[2][j];
    }
  }
}

// ------- K3b: project_out (170 -> 64) via MFMA -------
__global__ __launch_bounds__(256) void k_projout2(const u16* __restrict__ gbuf,
                                                  const u16* __restrict__ wof,
                                                  float* __restrict__ out, int hb) {
  const int b = blockIdx.x >> 7;                  // 128 blocks (rows) per batch
  const int p0 = (blockIdx.x & 127) << 8;
  const int w = threadIdx.x >> 6;
  const int lane = threadIdx.x & 63;
  const int lm = lane & 15, lh = lane >> 4;
  const size_t BW = (size_t)BAND * WID;
  const u16* gb = gbuf + (size_t)b * HID * BW + p0 + w*64 + lm;

  f32x4 acc[4][4];
  #pragma unroll
  for (int mt = 0; mt < 4; ++mt)
    #pragma unroll
    for (int ng = 0; ng < 4; ++ng)
      acc[mt][ng] = (f32x4){0.f,0.f,0.f,0.f};

  #pragma unroll
  for (int kc = 0; kc < 6; ++kc) {
    s16x8 A[4];
    #pragma unroll
    for (int mt = 0; mt < 4; ++mt)
      A[mt] = *(const s16x8*)(wof + ((mt*6 + kc)*64 + lane)*8);
    #pragma unroll
    for (int ng = 0; ng < 4; ++ng) {
      s16x8 Bf;
      #pragma unroll
      for (int r = 0; r < 8; ++r) {
        int c = kc*32 + lh*8 + r;
        if (kc == 5) c = min(c, HID - 1);          // A zero-padded for k>=170
        Bf[r] = (short)gb[(size_t)c * BW + ng*16];
      }
      #pragma unroll
      for (int mt = 0; mt < 4; ++mt)
        acc[mt][ng] = __builtin_amdgcn_mfma_f32_16x16x32_bf16(A[mt], Bf, acc[mt][ng], 0,0,0);
    }
  }
  float* ob = out + (size_t)b * 64 * HW + (size_t)hb * WID + p0 + w*64 + lm;
  #pragma unroll
  for (int mt = 0; mt < 4; ++mt)
    #pragma unroll
    for (int ng = 0; ng < 4; ++ng)
      #pragma unroll
      for (int r = 0; r < 4; ++r)
        ob[(size_t)(mt*16 + lh*4 + r) * HW + ng*16] = acc[mt][ng][r];
}

extern "C" void kernel_launch(void* const* d_in, const int* in_sizes, int n_in,
                              void* d_out, int out_size, void* d_ws, size_t ws_size,
                              hipStream_t stream) {
  const float* x     = (const float*)d_in[0];
  const float* w_in  = (const float*)d_in[1];
  const float* w_dw  = (const float*)d_in[2];
  const float* fw    = (const float*)d_in[3];
  const float* w_out = (const float*)d_in[4];
  float* out = (float*)d_out;

  char* ws = (char*)d_ws;
  u16* mid    = (u16*)ws;                                  // 178,257,920 B
  u16* gbuf   = (u16*)(ws + 178257920);                    // 44,564,480 B
  u16* xt     = (u16*)(ws + 178257920);                    // aliases gbuf (used before it)
  u16* wof    = (u16*)(ws + 178257920 + 44564480);         // 24,576 B (w_out A-frags)
  u16* mfrag  = (u16*)(ws + 178257920 + 44564480 + 43520); // 2,785,280 B
  u16* wfrag  = (u16*)(ws + 178257920 + 44564480 + 43520 + 2785280); // 45,056 B

  k_wofrag<<<1, 256, 0, stream>>>(w_out, wof);
  k_wfrag<<<1, 256, 0, stream>>>(w_in, wfrag);
  k_mfrag<<<C2, 256, 0, stream>>>(fw, mfrag);
  k_xt<<<NB*256, 256, 0, stream>>>(x, xt);
  k_fused<<<NB*64, 512, 0, stream>>>(xt, wfrag, mfrag, mid);
  for (int sb = 0; sb < 2; ++sb) {
    const int hb = sb * BAND;
    k_gate<<<NB*HID*8, 256, 0, stream>>>(mid, w_dw, gbuf, hb);
    k_projout2<<<NB*BAND, 256, 0, stream>>>(gbuf, wof, out, hb);   // 256 px per block
  }
}